// Round 4
// baseline (4529.097 us; speedup 1.0000x reference)
//
#include <hip/hip_runtime.h>
#include <hip/hip_fp16.h>

// DAG phenotype evaluation: sentinel dataflow + completion watermark.
//
// vals[N_NODES][64]: packed half2(b, b+64), 256 B/row. SENTW = NaN|NaN = "not
// ready". Producers publish with coherent (write-through) stores; then
// vmcnt(0) + device-scope atomicAdd on their 1024-node page counter; the
// wave that fills a page advances the watermark WM ("all nodes < WM done")
// by CAS. Consumers read WM once (1 coherent 4B load), gather preds < WM
// with PLAIN CACHED loads (L2/L3-served — the bulk, ~77%), and only preds
// >= WM via the coherent sentinel poll with s_sleep backoff.
//
// Staleness safety of plain loads: they only target rows already final in
// L3; consumer L2s cannot hold stale copies (init's dirty lines are flushed
// at its kernel-end release; coherent ops don't allocate into L2; plain
// loads never touch incomplete rows). Compiler safety: plain loads are
// asm volatile (cannot be hoisted above the WM-dependent branch), followed
// by s_waitcnt vmcnt(0) + sched_barrier(0) before use.
//
// Deadlock-free: nodes claimed in increasing order from an atomic counter,
// so the lowest uncomputed node always belongs to a running wave whose
// (lower-indexed) preds are complete.

#define N_NODES 100000
#define N_IN    1024
#define N_OUT   1024
#define FAN_IN  32
#define NPAIR   64              // BATCH/2 packed slots per row
#define N_TODO  (N_NODES - N_IN)
#define SENTW   0xFFFFFFFFu
#define PGSZ    1024
#define PGSHIFT 10
#define NPAGES  ((N_TODO + PGSZ - 1) / PGSZ)   // 97

// ws: [0,4) claim counter | [64,68) wm_page | [128,128+4*NPAGES) page_cnt
//     [4096, +25.6MB) vals
#define OFS_WM   64
#define OFS_PC   128
#define OFS_VALS 4096

__global__ __launch_bounds__(256) void init_kernel(const float* __restrict__ x,
                                                   unsigned* __restrict__ vals,
                                                   int* __restrict__ counter,
                                                   int* __restrict__ wm_page,
                                                   int* __restrict__ page_cnt) {
    const int tid = blockIdx.x * blockDim.x + threadIdx.x;
    if (tid == 0) { *counter = 0; *wm_page = 0; }
    if (tid < NPAGES) page_cnt[tid] = 0;
    // inputs: vals[i][b] = pack(half(x[b][i]), half(x[b+64][i]))
    if (tid < N_IN * NPAIR) {
        const int i = tid >> 6;
        const int b = tid & 63;
        __half2 h2 = __floats2half2_rn(x[b * N_IN + i], x[(b + 64) * N_IN + i]);
        vals[i * NPAIR + b] = *reinterpret_cast<unsigned*>(&h2);
    }
    // sentinel-fill all non-input rows
    uint4* p = (uint4*)(vals + (size_t)N_IN * NPAIR);
    const int total = N_TODO * NPAIR / 4;
    const uint4 s4 = make_uint4(SENTW, SENTW, SENTW, SENTW);
    for (int t = tid; t < total; t += gridDim.x * blockDim.x)
        p[t] = s4;
}

__global__ __launch_bounds__(256, 4) void dag_kernel(const float* __restrict__ weights,
                                                     const int* __restrict__ in_ids,
                                                     unsigned* __restrict__ vals,
                                                     int* __restrict__ counter,
                                                     int* __restrict__ wm_page,
                                                     int* __restrict__ page_cnt,
                                                     float* __restrict__ out) {
    const int lane = threadIdx.x & 63;

    int idx = 0;
    if (lane == 0) idx = atomicAdd(counter, 1);
    idx = __builtin_amdgcn_readfirstlane(idx);

    while (idx < N_TODO) {
        int nxt = 0;
        if (lane == 0) nxt = atomicAdd(counter, 1);

        const int  node  = N_IN + idx;
        const long wbase = (long)node * FAN_IN;

        int ids[FAN_IN];
#pragma unroll
        for (int k = 0; k < FAN_IN; ++k)
            ids[k] = in_ids[wbase + k];          // uniform -> SGPR loads

        // watermark read (single hot line; 64-lane same-address load coalesces)
        int wmp = __hip_atomic_load(wm_page, __ATOMIC_RELAXED, __HIP_MEMORY_SCOPE_AGENT);
        const int wmn = __builtin_amdgcn_readfirstlane(N_IN + (wmp << PGSHIFT));

        // split gather: plain cached loads for preds < WM (bulk), coherent otherwise
        unsigned v[FAN_IN];
        unsigned need = 0;                       // uniform: rows on coherent path
#pragma unroll
        for (int k = 0; k < FAN_IN; ++k) {
            const unsigned* p = vals + (long)ids[k] * NPAIR + lane;
            if (ids[k] < wmn) {
                asm volatile("global_load_dword %0, %1, off"
                             : "=v"(v[k]) : "v"(p));
            } else {
                v[k] = __hip_atomic_load(p, __ATOMIC_RELAXED, __HIP_MEMORY_SCOPE_AGENT);
                need |= 1u << k;
            }
        }
        asm volatile("s_waitcnt vmcnt(0)" ::: "memory");
        __builtin_amdgcn_sched_barrier(0);

        // sentinel poll with backoff, only over the coherent subset
        while (need) {
            unsigned got = 0;
#pragma unroll
            for (int k = 0; k < FAN_IN; ++k)
                if ((need >> k) & 1u)
                    if (__all(v[k] != SENTW)) got |= 1u << k;
            need &= ~got;
            if (!need) break;
            __builtin_amdgcn_s_sleep(2);
#pragma unroll
            for (int k = 0; k < FAN_IN; ++k)
                if ((need >> k) & 1u)
                    v[k] = __hip_atomic_load(vals + (long)ids[k] * NPAIR + lane,
                                             __ATOMIC_RELAXED, __HIP_MEMORY_SCOPE_AGENT);
        }

        // dot + relu in fp32 (weights uniform -> SGPR operand)
        float acc0 = 0.f, acc1 = 0.f;
#pragma unroll
        for (int k = 0; k < FAN_IN; ++k) {
            const float  wk = weights[wbase + k];
            const __half2 h2 = *reinterpret_cast<const __half2*>(&v[k]);
            const float2  f  = __half22float2(h2);
            acc0 = fmaf(wk, f.x, acc0);
            acc1 = fmaf(wk, f.y, acc1);
        }
        acc0 = fmaxf(acc0, 0.f);
        acc1 = fmaxf(acc1, 0.f);

        // publish (coherent write-through)
        __half2 hr = __floats2half2_rn(acc0, acc1);
        __hip_atomic_store(vals + (long)node * NPAIR + lane,
                           *reinterpret_cast<unsigned*>(&hr),
                           __ATOMIC_RELAXED, __HIP_MEMORY_SCOPE_AGENT);

        // output-layer nodes scatter fp32 into d_out [BATCH, N_OUT]
        if (node >= N_NODES - N_OUT) {
            const int j = node - (N_NODES - N_OUT);
            out[lane * N_OUT + j]        = acc0;
            out[(lane + 64) * N_OUT + j] = acc1;
        }

        // page accounting: value must be in L3 before its count increment
        asm volatile("s_waitcnt vmcnt(0)" ::: "memory");
        if (lane == 0) {
            const int pg = idx >> PGSHIFT;
            const int ps = min(PGSZ, N_TODO - (pg << PGSHIFT));
            int old = __hip_atomic_fetch_add(page_cnt + pg, 1,
                                             __ATOMIC_RELAXED, __HIP_MEMORY_SCOPE_AGENT);
            if (old == ps - 1) {
                // this wave completed page pg: advance the watermark
                for (;;) {
                    int cur = __hip_atomic_load(wm_page, __ATOMIC_RELAXED,
                                                __HIP_MEMORY_SCOPE_AGENT);
                    if (cur >= NPAGES) break;
                    int fps = min(PGSZ, N_TODO - (cur << PGSHIFT));
                    int cnt = __hip_atomic_load(page_cnt + cur, __ATOMIC_RELAXED,
                                                __HIP_MEMORY_SCOPE_AGENT);
                    if (cnt < fps) break;
                    int expected = cur;
                    __hip_atomic_compare_exchange_strong(wm_page, &expected, cur + 1,
                                                         __ATOMIC_RELAXED, __ATOMIC_RELAXED,
                                                         __HIP_MEMORY_SCOPE_AGENT);
                }
            }
        }

        idx = __builtin_amdgcn_readfirstlane(nxt);
    }
}

extern "C" void kernel_launch(void* const* d_in, const int* in_sizes, int n_in,
                              void* d_out, int out_size, void* d_ws, size_t ws_size,
                              hipStream_t stream) {
    const float* x       = (const float*)d_in[0];
    const float* weights = (const float*)d_in[1];
    const int*   in_ids  = (const int*)d_in[2];
    float*       out     = (float*)d_out;

    int*      counter = (int*)d_ws;
    int*      wm_page = (int*)((char*)d_ws + OFS_WM);
    int*      page_cnt= (int*)((char*)d_ws + OFS_PC);
    unsigned* vals    = (unsigned*)((char*)d_ws + OFS_VALS);

    init_kernel<<<2048, 256, 0, stream>>>(x, vals, counter, wm_page, page_cnt);
    dag_kernel<<<1024, 256, 0, stream>>>(weights, in_ids, vals, counter,
                                         wm_page, page_cnt, out);
}

// Round 5
// 1291.467 us; speedup vs baseline: 3.5069x; 3.5069x over previous
//
#include <hip/hip_runtime.h>
#include <hip/hip_fp16.h>

// DAG phenotype evaluation: sentinel dataflow + completion watermark.
// Round-5 fix: PAD all control variables to separate cache lines (round 4
// had claim counter + wm_page on ONE line -> every node serialized on a
// single coherence-point line = 4.6 ms). Also: 2048 waves (smaller claim
// window -> fewer polled preds), s_sleep(1) backoff.
//
// vals[N_NODES][64]: packed half2(b, b+64), 256 B/row. SENTW = NaN|NaN =
// "not ready". Producers publish with coherent (write-through) stores, wait
// vmcnt(0), then atomicAdd their 1024-node page counter; the wave that
// fills a page advances watermark WM ("all nodes < WM done") by CAS.
// Consumers read WM once per node, gather preds < WM with PLAIN CACHED
// loads (L2-allocating — the bulk), preds >= WM via coherent sentinel poll.
//
// Staleness safety of plain loads: dag_kernel's launch begins with an
// implicit agent acquire (L1/L2 invalidate), so no lines survive from init
// or previous calls; during execution plain loads only target rows already
// final (WM-guarded), so no stale line can be cached. asm volatile prevents
// compiler speculation above the WM branch; vmcnt(0)+sched_barrier before use.
//
// Deadlock-free: nodes claimed in increasing order from an atomic counter;
// the lowest uncomputed node always belongs to a running wave whose
// (lower-indexed) preds are all complete.

#define N_NODES 100000
#define N_IN    1024
#define N_OUT   1024
#define FAN_IN  32
#define NPAIR   64              // BATCH/2 packed slots per row
#define N_TODO  (N_NODES - N_IN)
#define SENTW   0xFFFFFFFFu
#define PGSZ    1024
#define PGSHIFT 10
#define NPAGES  ((N_TODO + PGSZ - 1) / PGSZ)   // 97

// ws layout (bytes) — every control word on its own 256B region:
//   [0]      claim counter
//   [4096]   wm_page
//   [8192]   page_cnt[97], stride 256 B (64 ints)
//   [65536]  vals (25.6 MB)
#define OFS_WM    4096
#define OFS_PC    8192
#define PC_STRIDE 64
#define OFS_VALS  65536

__global__ __launch_bounds__(256) void init_kernel(const float* __restrict__ x,
                                                   unsigned* __restrict__ vals,
                                                   int* __restrict__ counter,
                                                   int* __restrict__ wm_page,
                                                   int* __restrict__ page_cnt) {
    const int tid = blockIdx.x * blockDim.x + threadIdx.x;
    if (tid == 0) { *counter = 0; *wm_page = 0; }
    if (tid < NPAGES) page_cnt[tid * PC_STRIDE] = 0;
    // inputs: vals[i][b] = pack(half(x[b][i]), half(x[b+64][i]))
    if (tid < N_IN * NPAIR) {
        const int i = tid >> 6;
        const int b = tid & 63;
        __half2 h2 = __floats2half2_rn(x[b * N_IN + i], x[(b + 64) * N_IN + i]);
        vals[i * NPAIR + b] = *reinterpret_cast<unsigned*>(&h2);
    }
    // sentinel-fill all non-input rows
    uint4* p = (uint4*)(vals + (size_t)N_IN * NPAIR);
    const int total = N_TODO * NPAIR / 4;
    const uint4 s4 = make_uint4(SENTW, SENTW, SENTW, SENTW);
    for (int t = tid; t < total; t += gridDim.x * blockDim.x)
        p[t] = s4;
}

__global__ __launch_bounds__(256, 4) void dag_kernel(const float* __restrict__ weights,
                                                     const int* __restrict__ in_ids,
                                                     unsigned* __restrict__ vals,
                                                     int* __restrict__ counter,
                                                     int* __restrict__ wm_page,
                                                     int* __restrict__ page_cnt,
                                                     float* __restrict__ out) {
    const int lane = threadIdx.x & 63;

    int idx = 0;
    if (lane == 0) idx = atomicAdd(counter, 1);
    idx = __builtin_amdgcn_readfirstlane(idx);

    while (idx < N_TODO) {
        int nxt = 0;
        if (lane == 0) nxt = atomicAdd(counter, 1);

        const int  node  = N_IN + idx;
        const long wbase = (long)node * FAN_IN;

        int ids[FAN_IN];
#pragma unroll
        for (int k = 0; k < FAN_IN; ++k)
            ids[k] = in_ids[wbase + k];          // uniform -> s_load

        // watermark read (dedicated line; 64-lane same-address load merges)
        int wmp = __hip_atomic_load(wm_page, __ATOMIC_RELAXED, __HIP_MEMORY_SCOPE_AGENT);
        const int wmn = __builtin_amdgcn_readfirstlane(N_IN + (wmp << PGSHIFT));

        // split gather: plain cached loads (<WM, bulk) vs coherent (>=WM)
        unsigned v[FAN_IN];
        unsigned need = 0;                       // uniform bitmask
#pragma unroll
        for (int k = 0; k < FAN_IN; ++k) {
            const unsigned* p = vals + (long)ids[k] * NPAIR + lane;
            if (ids[k] < wmn) {
                asm volatile("global_load_dword %0, %1, off"
                             : "=v"(v[k]) : "v"(p));
            } else {
                v[k] = __hip_atomic_load(p, __ATOMIC_RELAXED, __HIP_MEMORY_SCOPE_AGENT);
                need |= 1u << k;
            }
        }
        asm volatile("s_waitcnt vmcnt(0)" ::: "memory");
        __builtin_amdgcn_sched_barrier(0);

        // sentinel poll with backoff over the coherent subset only
        while (need) {
            unsigned got = 0;
#pragma unroll
            for (int k = 0; k < FAN_IN; ++k)
                if ((need >> k) & 1u)
                    if (__all(v[k] != SENTW)) got |= 1u << k;
            need &= ~got;
            if (!need) break;
            __builtin_amdgcn_s_sleep(1);
#pragma unroll
            for (int k = 0; k < FAN_IN; ++k)
                if ((need >> k) & 1u)
                    v[k] = __hip_atomic_load(vals + (long)ids[k] * NPAIR + lane,
                                             __ATOMIC_RELAXED, __HIP_MEMORY_SCOPE_AGENT);
        }

        // dot + relu in fp32 (weights uniform -> SGPR operand)
        float acc0 = 0.f, acc1 = 0.f;
#pragma unroll
        for (int k = 0; k < FAN_IN; ++k) {
            const float  wk = weights[wbase + k];
            const __half2 h2 = *reinterpret_cast<const __half2*>(&v[k]);
            const float2  f  = __half22float2(h2);
            acc0 = fmaf(wk, f.x, acc0);
            acc1 = fmaf(wk, f.y, acc1);
        }
        acc0 = fmaxf(acc0, 0.f);
        acc1 = fmaxf(acc1, 0.f);

        // publish (coherent write-through)
        __half2 hr = __floats2half2_rn(acc0, acc1);
        __hip_atomic_store(vals + (long)node * NPAIR + lane,
                           *reinterpret_cast<unsigned*>(&hr),
                           __ATOMIC_RELAXED, __HIP_MEMORY_SCOPE_AGENT);

        // output-layer nodes scatter fp32 into d_out [BATCH, N_OUT]
        if (node >= N_NODES - N_OUT) {
            const int j = node - (N_NODES - N_OUT);
            out[lane * N_OUT + j]        = acc0;
            out[(lane + 64) * N_OUT + j] = acc1;
        }

        // page accounting: value must be at the coherence point first
        asm volatile("s_waitcnt vmcnt(0)" ::: "memory");
        if (lane == 0) {
            const int pg = idx >> PGSHIFT;
            const int ps = min(PGSZ, N_TODO - (pg << PGSHIFT));
            int old = __hip_atomic_fetch_add(page_cnt + (size_t)pg * PC_STRIDE, 1,
                                             __ATOMIC_RELAXED, __HIP_MEMORY_SCOPE_AGENT);
            if (old == ps - 1) {
                for (;;) {   // advance watermark over all consecutively-full pages
                    int cur = __hip_atomic_load(wm_page, __ATOMIC_RELAXED,
                                                __HIP_MEMORY_SCOPE_AGENT);
                    if (cur >= NPAGES) break;
                    int fps = min(PGSZ, N_TODO - (cur << PGSHIFT));
                    int cnt = __hip_atomic_load(page_cnt + (size_t)cur * PC_STRIDE,
                                                __ATOMIC_RELAXED, __HIP_MEMORY_SCOPE_AGENT);
                    if (cnt < fps) break;
                    int expected = cur;
                    __hip_atomic_compare_exchange_strong(wm_page, &expected, cur + 1,
                                                         __ATOMIC_RELAXED, __ATOMIC_RELAXED,
                                                         __HIP_MEMORY_SCOPE_AGENT);
                }
            }
        }

        idx = __builtin_amdgcn_readfirstlane(nxt);
    }
}

extern "C" void kernel_launch(void* const* d_in, const int* in_sizes, int n_in,
                              void* d_out, int out_size, void* d_ws, size_t ws_size,
                              hipStream_t stream) {
    const float* x       = (const float*)d_in[0];
    const float* weights = (const float*)d_in[1];
    const int*   in_ids  = (const int*)d_in[2];
    float*       out     = (float*)d_out;

    int*      counter = (int*)d_ws;
    int*      wm_page = (int*)((char*)d_ws + OFS_WM);
    int*      page_cnt= (int*)((char*)d_ws + OFS_PC);
    unsigned* vals    = (unsigned*)((char*)d_ws + OFS_VALS);

    init_kernel<<<2048, 256, 0, stream>>>(x, vals, counter, wm_page, page_cnt);
    // 512 blocks x 256 threads = 2048 waves (smaller claim window -> fewer
    // coherent-path polls; still ~5x the per-level parallelism)
    dag_kernel<<<512, 256, 0, stream>>>(weights, in_ids, vals, counter,
                                        wm_page, page_cnt, out);
}